// Round 1
// baseline (499.994 us; speedup 1.0000x reference)
//
#include <hip/hip_runtime.h>
#include <hip/hip_bf16.h>
#include <stdint.h>

#define N_IMG 16
#define C_IN  512
#define C_OUT 512
#define H_IN  64
#define W_IN  64
#define OH    32
#define OW    32
#define PIX   (N_IMG*OH*OW)        // 16384

// padded blurred-activation layout: [n][h+1 (65)][par (2)][ow'+1 (33)][ci (512)] bf16
#define YPH 65
#define YPW 33
#define Y_SLOTS (N_IMG*YPH*2*YPW)  // 68640 pixel slots, each C_IN bf16

#define W2_ELEMS (9*C_OUT*C_IN)    // 2359296
#define W2_BYTES (W2_ELEMS*2)      // 4718592 (256B aligned)

typedef __attribute__((ext_vector_type(8))) __bf16 bf16x8;
typedef __attribute__((ext_vector_type(4))) float  f32x4;

__device__ inline void gload_lds16(const void* g, void* l) {
  __builtin_amdgcn_global_load_lds(
      (const __attribute__((address_space(1))) void*)g,
      (__attribute__((address_space(3))) void*)l, 16, 0, 0);
}

// ---------------- weight prep: w[co][ci][kh][kw]*f32 -> w2[t][co][ci] bf16 * (1/1536)
__global__ void prep_w_kernel(const float* __restrict__ w, __hip_bfloat16* __restrict__ w2) {
  int idx = blockIdx.x * 256 + threadIdx.x;
  if (idx >= W2_ELEMS) return;
  int ci  = idx & (C_IN-1);
  int rem = idx >> 9;
  int co  = rem & (C_OUT-1);
  int t   = rem >> 9;
  float v = w[((size_t)co*C_IN + ci)*9 + t] * (1.0f/1536.0f);
  w2[idx] = __float2bfloat16(v);
}

// ---------------- zero the halo (row -1 and col -1) of yt; ws is poisoned each call
__global__ void zero_pad_kernel(__hip_bfloat16* __restrict__ yt) {
  int sid = blockIdx.x;
  size_t slot;
  if (sid < N_IMG*2*YPW) {                    // ridx==0 (h=-1), all par,c
    int n = sid / (2*YPW);
    int v = sid % (2*YPW);
    slot = (size_t)n * (YPH*2*YPW) + v;       // ((n*65+0)*2+par)*33+c
  } else {                                    // cidx==0 (col -1), all rows,par
    int u = sid - N_IMG*2*YPW;
    int n = u / (YPH*2);
    int v = u % (YPH*2);
    slot = ((size_t)n*(YPH*2) + v) * YPW;
  }
  ((unsigned*)yt)[slot*256 + threadIdx.x] = 0u;  // 512 bf16 = 256 dwords
}

// ---------------- FIR blur + transpose to channel-last parity-split padded layout
__global__ void blur_kernel(const float* __restrict__ x, __hip_bfloat16* __restrict__ yt) {
  __shared__ float ylds[64][65];
  const int h   = blockIdx.x;          // output full-res row 0..63
  const int cib = blockIdx.y * 64;     // ci chunk
  const int n   = blockIdx.z;
  const int w   = threadIdx.x & 63;
  const int g   = threadIdx.x >> 6;
  const float fw[4] = {1.f, 3.f, 3.f, 1.f};

  for (int cl = g; cl < 64; cl += 4) {
    const float* xb = x + ((size_t)(n*C_IN + cib + cl)*H_IN)*W_IN;
    float acc = 0.f;
#pragma unroll
    for (int a = 0; a < 4; ++a) {
      int r = h + a - 2;
      if (r < 0 || r >= H_IN) continue;
      const float* xr = xb + (size_t)r*W_IN;
      float hs = 0.f;
#pragma unroll
      for (int b = 0; b < 4; ++b) {
        int c = w + b - 2;
        float xv = (c >= 0 && c < W_IN) ? xr[c] : 0.f;
        hs = fmaf(fw[b], xv, hs);
      }
      acc = fmaf(fw[a], hs, acc);
    }
    ylds[cl][w] = acc * (1.0f/64.0f);
  }
  __syncthreads();

  // transposed write-out: thread -> (pixel w-coord p, ci quarter q)
  const int p   = threadIdx.x >> 2;    // 0..63 full-res col
  const int q   = threadIdx.x & 3;
  const int par = p & 1;
  const int c   = p >> 1;
  size_t slot = (((size_t)n*YPH + (h+1))*2 + par)*YPW + (c+1);
  alignas(16) __hip_bfloat16 tmp[16];
#pragma unroll
  for (int j = 0; j < 16; ++j)
    tmp[j] = __float2bfloat16(ylds[q*16 + j][p]);
  uint4* dst  = (uint4*)(yt + slot*C_IN + cib + q*16);
  uint4* srcv = (uint4*)tmp;
  dst[0] = srcv[0];
  dst[1] = srcv[1];
}

// ---------------- implicit-GEMM conv: out[co][pix] = sum_t sum_ci w2[t][co][ci]*y[pix(t)][ci]
__global__ void conv_kernel(const __hip_bfloat16* __restrict__ w2,
                            const __hip_bfloat16* __restrict__ yt,
                            const float* __restrict__ bias,
                            float* __restrict__ out) {
  __shared__ __hip_bfloat16 Alds[128*64];   // 16 KB: [co row][ci] with XOR seg swizzle
  __shared__ __hip_bfloat16 Blds[128*64];   // 16 KB: [pix row][ci]
  const int tid  = threadIdx.x;
  const int lane = tid & 63;
  const int wv   = tid >> 6;     // 4 waves
  const int wm   = wv & 1;
  const int wn   = wv >> 1;
  const int cob0 = blockIdx.y * 128;
  const int pixb = blockIdx.x * 128;
  const int quad = lane >> 4;
  const int wvb  = tid & 192;    // wave*64

  // staging precompute: slot s = i*256+tid; row=s>>3, pos=s&7, loads gseg=pos^(row&7)
  size_t aoff[4];
  int    bseg8[4], bn65[4], boh2[4], bow_[4];
  char*  ldsAdst[4];
  char*  ldsBdst[4];
#pragma unroll
  for (int i = 0; i < 4; ++i) {
    int s = i*256 + tid;
    int r = s >> 3;
    int pp = s & 7;
    int gg = pp ^ (r & 7);
    aoff[i] = (size_t)(cob0 + r)*C_IN + gg*8;
    int gp = pixb + r;
    bn65[i] = (gp >> 10) * YPH;
    boh2[i] = ((gp >> 5) & 31) * 2;
    bow_[i] = gp & 31;
    bseg8[i] = gg*8;
    ldsAdst[i] = (char*)Alds + (size_t)(i*256 + wvb)*16;
    ldsBdst[i] = (char*)Blds + (size_t)(i*256 + wvb)*16;
  }

  f32x4 acc[4][4];
  const f32x4 zero = {0.f, 0.f, 0.f, 0.f};
#pragma unroll
  for (int mi = 0; mi < 4; ++mi)
#pragma unroll
    for (int ni = 0; ni < 4; ++ni) acc[mi][ni] = zero;

  for (int t = 0; t < 9; ++t) {
    const int kh  = t / 3;
    const int kw  = t - kh*3;
    const int par = (kw == 1) ? 0 : 1;
    const int d   = (kw == 0) ? 0 : 1;
    const __hip_bfloat16* wt = w2 + (size_t)t * C_OUT * C_IN;
    size_t boff[4];
#pragma unroll
    for (int i = 0; i < 4; ++i) {
      size_t slot = ((size_t)(bn65[i] + boh2[i] + kh)*2 + par)*YPW + bow_[i] + d;
      boff[i] = slot*C_IN + bseg8[i];
    }
    for (int cib = 0; cib < C_IN; cib += 64) {
      __syncthreads();
#pragma unroll
      for (int i = 0; i < 4; ++i) gload_lds16(wt + aoff[i] + cib, ldsAdst[i]);
#pragma unroll
      for (int i = 0; i < 4; ++i) gload_lds16(yt + boff[i] + cib, ldsBdst[i]);
      __syncthreads();
#pragma unroll
      for (int kk = 0; kk < 2; ++kk) {
        bf16x8 af[4], bfr[4];
#pragma unroll
        for (int mi = 0; mi < 4; ++mi) {
          int r = wm*64 + mi*16 + (lane & 15);
          int gsg = kk*4 + quad;
          af[mi] = *(const bf16x8*)((const char*)Alds + r*128 + ((gsg ^ (r & 7))*16));
        }
#pragma unroll
        for (int ni = 0; ni < 4; ++ni) {
          int r = wn*64 + ni*16 + (lane & 15);
          int gsg = kk*4 + quad;
          bfr[ni] = *(const bf16x8*)((const char*)Blds + r*128 + ((gsg ^ (r & 7))*16));
        }
#pragma unroll
        for (int mi = 0; mi < 4; ++mi)
#pragma unroll
          for (int ni = 0; ni < 4; ++ni)
            acc[mi][ni] = __builtin_amdgcn_mfma_f32_16x16x32_bf16(af[mi], bfr[ni], acc[mi][ni], 0, 0, 0);
      }
    }
  }

  // epilogue: D layout col(pixel)=lane&15, row(co)=(lane>>4)*4+reg
#pragma unroll
  for (int mi = 0; mi < 4; ++mi) {
#pragma unroll
    for (int reg = 0; reg < 4; ++reg) {
      int co = cob0 + wm*64 + mi*16 + quad*4 + reg;
      float bv = bias[co];
#pragma unroll
      for (int ni = 0; ni < 4; ++ni) {
        int gp  = pixb + wn*64 + ni*16 + (lane & 15);
        int n   = gp >> 10;
        int ohw = gp & 1023;
        float v = acc[mi][ni][reg] + bv;
        v = (v >= 0.f ? v : 0.2f*v) * 1.41421356f;
        out[(((size_t)n*C_OUT + co) << 10) + ohw] = v;
      }
    }
  }
}

extern "C" void kernel_launch(void* const* d_in, const int* in_sizes, int n_in,
                              void* d_out, int out_size, void* d_ws, size_t ws_size,
                              hipStream_t stream) {
  const float* x    = (const float*)d_in[0];
  const float* w    = (const float*)d_in[1];
  const float* bias = (const float*)d_in[2];
  // d_in[3] = fir; values fixed by module config ([1,3,3,1] outer /64), folded in.
  float* out = (float*)d_out;
  __hip_bfloat16* w2 = (__hip_bfloat16*)d_ws;
  __hip_bfloat16* yt = (__hip_bfloat16*)((char*)d_ws + W2_BYTES);

  prep_w_kernel<<<(W2_ELEMS + 255)/256, 256, 0, stream>>>(w, w2);
  zero_pad_kernel<<<N_IMG*2*YPW + N_IMG*YPH*2, 256, 0, stream>>>(yt);
  blur_kernel<<<dim3(64, 8, 16), 256, 0, stream>>>(x, yt);
  conv_kernel<<<dim3(PIX/128, C_OUT/128), 256, 0, stream>>>(w2, yt, bias, out);
}

// Round 2
// 349.325 us; speedup vs baseline: 1.4313x; 1.4313x over previous
//
#include <hip/hip_runtime.h>
#include <hip/hip_bf16.h>
#include <stdint.h>

#define N_IMG 16
#define C_IN  512
#define C_OUT 512
#define H_IN  64
#define W_IN  64
#define OH    32
#define OW    32
#define PIX   (N_IMG*OH*OW)        // 16384

// padded blurred-activation layout: [n][h+1 (65)][par (2)][ow'+1 (33)][ci (512)] bf16
#define YPH 65
#define YPW 33
#define Y_SLOTS (N_IMG*YPH*2*YPW)  // 68640 pixel slots, each C_IN bf16

#define W2_ELEMS (9*C_OUT*C_IN)    // 2359296
#define W2_BYTES (W2_ELEMS*2)      // 4718592 (256B aligned)

typedef __attribute__((ext_vector_type(8))) __bf16 bf16x8;
typedef __attribute__((ext_vector_type(4))) float  f32x4;

__device__ inline void gload_lds16(const void* g, void* l) {
  __builtin_amdgcn_global_load_lds(
      (const __attribute__((address_space(1))) void*)g,
      (__attribute__((address_space(3))) void*)l, 16, 0, 0);
}

// ---------------- weight prep: w[co][ci][kh][kw]*f32 -> w2[t][co][ci] bf16 * (1/1536)
__global__ void prep_w_kernel(const float* __restrict__ w, __hip_bfloat16* __restrict__ w2) {
  int idx = blockIdx.x * 256 + threadIdx.x;
  if (idx >= W2_ELEMS) return;
  int ci  = idx & (C_IN-1);
  int rem = idx >> 9;
  int co  = rem & (C_OUT-1);
  int t   = rem >> 9;
  float v = w[((size_t)co*C_IN + ci)*9 + t] * (1.0f/1536.0f);
  w2[idx] = __float2bfloat16(v);
}

// ---------------- zero the halo (row -1 and col -1) of yt; ws is poisoned each call
__global__ void zero_pad_kernel(__hip_bfloat16* __restrict__ yt) {
  int sid = blockIdx.x;
  size_t slot;
  if (sid < N_IMG*2*YPW) {                    // ridx==0 (h=-1), all par,c
    int n = sid / (2*YPW);
    int v = sid % (2*YPW);
    slot = (size_t)n * (YPH*2*YPW) + v;       // ((n*65+0)*2+par)*33+c
  } else {                                    // cidx==0 (col -1), all rows,par
    int u = sid - N_IMG*2*YPW;
    int n = u / (YPH*2);
    int v = u % (YPH*2);
    slot = ((size_t)n*(YPH*2) + v) * YPW;
  }
  ((unsigned*)yt)[slot*256 + threadIdx.x] = 0u;  // 512 bf16 = 256 dwords
}

// ---------------- FIR blur, separable, register-streaming + LDS transpose
// grid: (row-tile 0..1, cib 0..15, n 0..15), block 256.
// thread: c = tid>>3 (ci in chunk), octet p8 = tid&7 (w = p8*8 .. +7)
__global__ __launch_bounds__(256) void blur_kernel(const float* __restrict__ x,
                                                   __hip_bfloat16* __restrict__ yt) {
  __shared__ float obuf[2][32][65];   // stride 65 -> 2-way bank aliasing (free)
  const int tid = threadIdx.x;
  const int c   = tid >> 3;
  const int p8  = tid & 7;
  const int w8  = p8 * 8;
  const int r0  = blockIdx.x * 32;
  const int cib = blockIdx.y;
  const int n   = blockIdx.z;
  const float* xc = x + ((size_t)(n*C_IN + cib*32 + c) * H_IN) * W_IN + w8;

  // repack mapping: 4 consecutive lanes cover one pixel's 64B (32 ci) write
  const int rp_oc  = tid & 3;
  const int rp_p   = tid >> 2;       // full-res col 0..63
  const int rp_par = rp_p & 1;
  const int rp_ch  = rp_p >> 1;

  float cur[8], nxt[8];
  float h1[8], h2[8], h3[8];         // horizontal-blurred rows r-1, r-2, r-3
#pragma unroll
  for (int j = 0; j < 8; ++j) { h1[j] = 0.f; h2[j] = 0.f; h3[j] = 0.f; }

  auto load_row = [&](int r, float* dst) {
    if (r >= 0 && r < H_IN) {
      const float4 a = *(const float4*)(xc + (size_t)r * W_IN);
      const float4 b = *(const float4*)(xc + (size_t)r * W_IN + 4);
      dst[0]=a.x; dst[1]=a.y; dst[2]=a.z; dst[3]=a.w;
      dst[4]=b.x; dst[5]=b.y; dst[6]=b.z; dst[7]=b.w;
    } else {
#pragma unroll
      for (int j = 0; j < 8; ++j) dst[j] = 0.f;
    }
  };

  load_row(r0 - 2, cur);
  for (int ri = 0; ri < 35; ++ri) {
    const int r = r0 - 2 + ri;
    if (ri < 34) load_row(r + 1, nxt);   // prefetch next row

    // horizontal 4-tap [1,3,3,1] via shuffles (neighbors within the 8-lane row group)
    float l2 = __shfl_up(cur[6], 1);
    float l1 = __shfl_up(cur[7], 1);
    float rr = __shfl_down(cur[0], 1);
    if (p8 == 0) { l2 = 0.f; l1 = 0.f; }
    if (p8 == 7) { rr = 0.f; }
    float hc[8];
    hc[0] = l2 + 3.f*(l1 + cur[0]) + cur[1];
    hc[1] = l1 + 3.f*(cur[0] + cur[1]) + cur[2];
#pragma unroll
    for (int j = 2; j < 7; ++j) hc[j] = cur[j-2] + 3.f*(cur[j-1] + cur[j]) + cur[j+1];
    hc[7] = cur[5] + 3.f*(cur[6] + cur[7]) + rr;

    if (ri >= 3) {
      const int h = r - 1;             // output row
      const int b = ri & 1;
#pragma unroll
      for (int j = 0; j < 8; ++j)
        obuf[b][c][w8 + j] = (h3[j] + 3.f*(h2[j] + h1[j]) + hc[j]) * (1.0f/64.0f);
      __syncthreads();
      alignas(16) __hip_bfloat16 t16[8];
#pragma unroll
      for (int j = 0; j < 8; ++j)
        t16[j] = __float2bfloat16(obuf[b][rp_oc*8 + j][rp_p]);
      size_t slot = ((size_t)(n*YPH + h + 1)*2 + rp_par)*YPW + rp_ch + 1;
      *(uint4*)(yt + slot*C_IN + cib*32 + rp_oc*8) = *(uint4*)t16;
      // no second barrier: double buffer + next iteration's barrier protects reuse
    }

    // rotate vertical window, advance prefetch
#pragma unroll
    for (int j = 0; j < 8; ++j) {
      h3[j] = h2[j]; h2[j] = h1[j]; h1[j] = hc[j]; cur[j] = nxt[j];
    }
  }
}

// ---------------- implicit-GEMM conv: out[co][pix] = sum_t sum_ci w2[t][co][ci]*y[pix(t)][ci]
__global__ void conv_kernel(const __hip_bfloat16* __restrict__ w2,
                            const __hip_bfloat16* __restrict__ yt,
                            const float* __restrict__ bias,
                            float* __restrict__ out) {
  __shared__ __hip_bfloat16 Alds[128*64];   // 16 KB: [co row][ci] with XOR seg swizzle
  __shared__ __hip_bfloat16 Blds[128*64];   // 16 KB: [pix row][ci]
  const int tid  = threadIdx.x;
  const int lane = tid & 63;
  const int wv   = tid >> 6;     // 4 waves
  const int wm   = wv & 1;
  const int wn   = wv >> 1;
  const int cob0 = blockIdx.y * 128;
  const int pixb = blockIdx.x * 128;
  const int quad = lane >> 4;
  const int wvb  = tid & 192;    // wave*64

  // staging precompute: slot s = i*256+tid; row=s>>3, pos=s&7, loads gseg=pos^(row&7)
  size_t aoff[4];
  int    bseg8[4], bn65[4], boh2[4], bow_[4];
  char*  ldsAdst[4];
  char*  ldsBdst[4];
#pragma unroll
  for (int i = 0; i < 4; ++i) {
    int s = i*256 + tid;
    int r = s >> 3;
    int pp = s & 7;
    int gg = pp ^ (r & 7);
    aoff[i] = (size_t)(cob0 + r)*C_IN + gg*8;
    int gp = pixb + r;
    bn65[i] = (gp >> 10) * YPH;
    boh2[i] = ((gp >> 5) & 31) * 2;
    bow_[i] = gp & 31;
    bseg8[i] = gg*8;
    ldsAdst[i] = (char*)Alds + (size_t)(i*256 + wvb)*16;
    ldsBdst[i] = (char*)Blds + (size_t)(i*256 + wvb)*16;
  }

  f32x4 acc[4][4];
  const f32x4 zero = {0.f, 0.f, 0.f, 0.f};
#pragma unroll
  for (int mi = 0; mi < 4; ++mi)
#pragma unroll
    for (int ni = 0; ni < 4; ++ni) acc[mi][ni] = zero;

  for (int t = 0; t < 9; ++t) {
    const int kh  = t / 3;
    const int kw  = t - kh*3;
    const int par = (kw == 1) ? 0 : 1;
    const int d   = (kw == 0) ? 0 : 1;
    const __hip_bfloat16* wt = w2 + (size_t)t * C_OUT * C_IN;
    size_t boff[4];
#pragma unroll
    for (int i = 0; i < 4; ++i) {
      size_t slot = ((size_t)(bn65[i] + boh2[i] + kh)*2 + par)*YPW + bow_[i] + d;
      boff[i] = slot*C_IN + bseg8[i];
    }
    for (int cib = 0; cib < C_IN; cib += 64) {
      __syncthreads();
#pragma unroll
      for (int i = 0; i < 4; ++i) gload_lds16(wt + aoff[i] + cib, ldsAdst[i]);
#pragma unroll
      for (int i = 0; i < 4; ++i) gload_lds16(yt + boff[i] + cib, ldsBdst[i]);
      __syncthreads();
#pragma unroll
      for (int kk = 0; kk < 2; ++kk) {
        bf16x8 af[4], bfr[4];
#pragma unroll
        for (int mi = 0; mi < 4; ++mi) {
          int r = wm*64 + mi*16 + (lane & 15);
          int gsg = kk*4 + quad;
          af[mi] = *(const bf16x8*)((const char*)Alds + r*128 + ((gsg ^ (r & 7))*16));
        }
#pragma unroll
        for (int ni = 0; ni < 4; ++ni) {
          int r = wn*64 + ni*16 + (lane & 15);
          int gsg = kk*4 + quad;
          bfr[ni] = *(const bf16x8*)((const char*)Blds + r*128 + ((gsg ^ (r & 7))*16));
        }
#pragma unroll
        for (int mi = 0; mi < 4; ++mi)
#pragma unroll
          for (int ni = 0; ni < 4; ++ni)
            acc[mi][ni] = __builtin_amdgcn_mfma_f32_16x16x32_bf16(af[mi], bfr[ni], acc[mi][ni], 0, 0, 0);
      }
    }
  }

  // epilogue: D layout col(pixel)=lane&15, row(co)=(lane>>4)*4+reg
#pragma unroll
  for (int mi = 0; mi < 4; ++mi) {
#pragma unroll
    for (int reg = 0; reg < 4; ++reg) {
      int co = cob0 + wm*64 + mi*16 + quad*4 + reg;
      float bv = bias[co];
#pragma unroll
      for (int ni = 0; ni < 4; ++ni) {
        int gp  = pixb + wn*64 + ni*16 + (lane & 15);
        int n   = gp >> 10;
        int ohw = gp & 1023;
        float v = acc[mi][ni][reg] + bv;
        v = (v >= 0.f ? v : 0.2f*v) * 1.41421356f;
        out[(((size_t)n*C_OUT + co) << 10) + ohw] = v;
      }
    }
  }
}

extern "C" void kernel_launch(void* const* d_in, const int* in_sizes, int n_in,
                              void* d_out, int out_size, void* d_ws, size_t ws_size,
                              hipStream_t stream) {
  const float* x    = (const float*)d_in[0];
  const float* w    = (const float*)d_in[1];
  const float* bias = (const float*)d_in[2];
  // d_in[3] = fir; values fixed by module config ([1,3,3,1] outer /64), folded in.
  float* out = (float*)d_out;
  __hip_bfloat16* w2 = (__hip_bfloat16*)d_ws;
  __hip_bfloat16* yt = (__hip_bfloat16*)((char*)d_ws + W2_BYTES);

  prep_w_kernel<<<(W2_ELEMS + 255)/256, 256, 0, stream>>>(w, w2);
  zero_pad_kernel<<<N_IMG*2*YPW + N_IMG*YPH*2, 256, 0, stream>>>(yt);
  blur_kernel<<<dim3(2, 16, 16), 256, 0, stream>>>(x, yt);
  conv_kernel<<<dim3(PIX/128, C_OUT/128), 256, 0, stream>>>(w2, yt, bias, out);
}

// Round 3
// 333.687 us; speedup vs baseline: 1.4984x; 1.0469x over previous
//
#include <hip/hip_runtime.h>
#include <hip/hip_bf16.h>
#include <stdint.h>

#define N_IMG 16
#define C_IN  512
#define C_OUT 512
#define H_IN  64
#define W_IN  64
#define OH    32
#define OW    32
#define PIX   (N_IMG*OH*OW)        // 16384

// padded blurred-activation layout: [n][h+1 (65)][par (2)][ow'+1 (33)][ci (512)] bf16
#define YPH 65
#define YPW 33

#define W2_ELEMS (9*C_OUT*C_IN)    // 2359296
#define W2_BYTES (W2_ELEMS*2)      // 4718592 (256B aligned)

typedef __attribute__((ext_vector_type(8))) __bf16 bf16x8;
typedef __attribute__((ext_vector_type(4))) float  f32x4;

__device__ inline void gload_lds16(const void* g, void* l) {
  __builtin_amdgcn_global_load_lds(
      (const __attribute__((address_space(1))) void*)g,
      (__attribute__((address_space(3))) void*)l, 16, 0, 0);
}

// ---------------- weight prep: w[co][ci][kh][kw]*f32 -> w2[t][co][ci] bf16 * (1/1536)
__global__ void prep_w_kernel(const float* __restrict__ w, __hip_bfloat16* __restrict__ w2) {
  int idx = blockIdx.x * 256 + threadIdx.x;
  if (idx >= W2_ELEMS) return;
  int ci  = idx & (C_IN-1);
  int rem = idx >> 9;
  int co  = rem & (C_OUT-1);
  int t   = rem >> 9;
  float v = w[((size_t)co*C_IN + ci)*9 + t] * (1.0f/1536.0f);
  w2[idx] = __float2bfloat16(v);
}

// ---------------- FIR blur, separable, register-streaming + LDS transpose
// grid: (row-tile 0..3, cib 0..15, n 0..15), block 256. Also zeroes yt halo.
// thread: c = tid>>3 (ci in chunk), octet p8 = tid&7 (w = p8*8 .. +7)
__global__ __launch_bounds__(256) void blur_kernel(const float* __restrict__ x,
                                                   __hip_bfloat16* __restrict__ yt) {
  __shared__ float obuf[2][32][65];   // stride 65 -> 2-way bank aliasing (free)
  const int tid = threadIdx.x;
  const int c   = tid >> 3;
  const int p8  = tid & 7;
  const int w8  = p8 * 8;
  const int r0  = blockIdx.x * 16;
  const int cib = blockIdx.y;
  const int n   = blockIdx.z;
  const float* xc = x + ((size_t)(n*C_IN + cib*32 + c) * H_IN) * W_IN + w8;

  // ---- halo zeroing (merged former zero_pad kernel) ----
  {
    const uint4 z4 = {0u, 0u, 0u, 0u};
    if (tid < 32) {                       // col-halo cidx=0 for this block's 16 rows
      int hh  = r0 + (tid >> 1);
      int par = tid & 1;
      size_t slot = (((size_t)n*YPH + hh + 1)*2 + par)*YPW;
      uint4* p = (uint4*)(yt + slot*C_IN + cib*32);
      p[0]=z4; p[1]=z4; p[2]=z4; p[3]=z4; // 32 ci bf16 = 64 B
    }
    if (blockIdx.x == 0 && tid < 66) {    // row-halo ridx=0, all (par, c)
      int par = tid / 33;
      int cc  = tid - par*33;
      size_t slot = ((size_t)n*YPH*2 + par)*YPW + cc;
      uint4* p = (uint4*)(yt + slot*C_IN + cib*32);
      p[0]=z4; p[1]=z4; p[2]=z4; p[3]=z4;
    }
  }

  // repack mapping: 4 consecutive lanes cover one pixel's 64B (32 ci) write
  const int rp_oc  = tid & 3;
  const int rp_p   = tid >> 2;       // full-res col 0..63
  const int rp_par = rp_p & 1;
  const int rp_ch  = rp_p >> 1;

  float cur[8], nxt[8];
  float h1[8], h2[8], h3[8];         // horizontal-blurred rows r-1, r-2, r-3
#pragma unroll
  for (int j = 0; j < 8; ++j) { h1[j] = 0.f; h2[j] = 0.f; h3[j] = 0.f; }

  auto load_row = [&](int r, float* dst) {
    if (r >= 0 && r < H_IN) {
      const float4 a = *(const float4*)(xc + (size_t)r * W_IN);
      const float4 b = *(const float4*)(xc + (size_t)r * W_IN + 4);
      dst[0]=a.x; dst[1]=a.y; dst[2]=a.z; dst[3]=a.w;
      dst[4]=b.x; dst[5]=b.y; dst[6]=b.z; dst[7]=b.w;
    } else {
#pragma unroll
      for (int j = 0; j < 8; ++j) dst[j] = 0.f;
    }
  };

  load_row(r0 - 2, cur);
  for (int ri = 0; ri < 19; ++ri) {
    const int r = r0 - 2 + ri;
    if (ri < 18) load_row(r + 1, nxt);   // prefetch next row

    // horizontal 4-tap [1,3,3,1] via shuffles (neighbors within the 8-lane row group)
    float l2 = __shfl_up(cur[6], 1);
    float l1 = __shfl_up(cur[7], 1);
    float rr = __shfl_down(cur[0], 1);
    if (p8 == 0) { l2 = 0.f; l1 = 0.f; }
    if (p8 == 7) { rr = 0.f; }
    float hc[8];
    hc[0] = l2 + 3.f*(l1 + cur[0]) + cur[1];
    hc[1] = l1 + 3.f*(cur[0] + cur[1]) + cur[2];
#pragma unroll
    for (int j = 2; j < 7; ++j) hc[j] = cur[j-2] + 3.f*(cur[j-1] + cur[j]) + cur[j+1];
    hc[7] = cur[5] + 3.f*(cur[6] + cur[7]) + rr;

    if (ri >= 3) {
      const int h = r - 1;             // output row
      const int b = ri & 1;
#pragma unroll
      for (int j = 0; j < 8; ++j)
        obuf[b][c][w8 + j] = (h3[j] + 3.f*(h2[j] + h1[j]) + hc[j]) * (1.0f/64.0f);
      __syncthreads();
      alignas(16) __hip_bfloat16 t16[8];
#pragma unroll
      for (int j = 0; j < 8; ++j)
        t16[j] = __float2bfloat16(obuf[b][rp_oc*8 + j][rp_p]);
      size_t slot = ((size_t)(n*YPH + h + 1)*2 + rp_par)*YPW + rp_ch + 1;
      *(uint4*)(yt + slot*C_IN + cib*32 + rp_oc*8) = *(uint4*)t16;
      // no second barrier: double buffer + next iteration's barrier protects reuse
    }

    // rotate vertical window, advance prefetch
#pragma unroll
    for (int j = 0; j < 8; ++j) {
      h3[j] = h2[j]; h2[j] = h1[j]; h1[j] = hc[j]; cur[j] = nxt[j];
    }
  }
}

// ---------------- implicit-GEMM conv, single-barrier double-buffered K-loop
// out[co][pix] = sum_t sum_ci w2[t][co][ci]*y[pix(t)][ci]
#define ABYTES (128*64*2)   // 16384 B per buffer
__global__ __launch_bounds__(256, 2) void conv_kernel(const __hip_bfloat16* __restrict__ w2,
                            const __hip_bfloat16* __restrict__ yt,
                            const float* __restrict__ bias,
                            float* __restrict__ out) {
  __shared__ __hip_bfloat16 Alds[2][128*64];   // 2 x 16 KB, XOR seg swizzle
  __shared__ __hip_bfloat16 Blds[2][128*64];   // 2 x 16 KB
  const int tid  = threadIdx.x;
  const int lane = tid & 63;
  const int wv   = tid >> 6;     // 4 waves
  const int wm   = wv & 1;
  const int wn   = wv >> 1;
  const int cob0 = blockIdx.y * 128;
  const int pixb = blockIdx.x * 128;
  const int quad = lane >> 4;
  const int wvb  = tid & 192;    // wave*64

  // staging precompute: slot s = i*256+tid; row=s>>3, pos=s&7, loads gseg=pos^(row&7)
  size_t aoff[4];
  int    bseg8[4], bn65[4], boh2[4], bow_[4];
  int    ldsOff[4];
#pragma unroll
  for (int i = 0; i < 4; ++i) {
    int s = i*256 + tid;
    int r = s >> 3;
    int pp = s & 7;
    int gg = pp ^ (r & 7);
    aoff[i] = (size_t)(cob0 + r)*C_IN + gg*8;
    int gp = pixb + r;
    bn65[i] = (gp >> 10) * YPH;
    boh2[i] = ((gp >> 5) & 31) * 2;
    bow_[i] = gp & 31;
    bseg8[i] = gg*8;
    ldsOff[i] = (i*256 + wvb)*16;   // wave-uniform base; HW adds lane*16
  }

  // stage chunk c (c = t*8 + cib64) into buffer b
  auto stage = [&](int c, int b) {
    const int t   = c >> 3;
    const int cib = (c & 7) << 6;
    const int kh  = (t * 11) >> 5;          // t/3 for t in 0..8
    const int kw  = t - kh*3;
    const int par = (kw == 1) ? 0 : 1;
    const int d   = (kw == 0) ? 0 : 1;
    const __hip_bfloat16* wt = w2 + (size_t)t * (C_OUT*C_IN) + cib;
#pragma unroll
    for (int i = 0; i < 4; ++i)
      gload_lds16(wt + aoff[i], (char*)Alds + b*ABYTES + ldsOff[i]);
#pragma unroll
    for (int i = 0; i < 4; ++i) {
      size_t slot = ((size_t)(bn65[i] + boh2[i] + kh)*2 + par)*YPW + bow_[i] + d;
      gload_lds16(yt + slot*C_IN + bseg8[i] + cib, (char*)Blds + b*ABYTES + ldsOff[i]);
    }
  };

  f32x4 acc[4][4];
  const f32x4 zero = {0.f, 0.f, 0.f, 0.f};
#pragma unroll
  for (int mi = 0; mi < 4; ++mi)
#pragma unroll
    for (int ni = 0; ni < 4; ++ni) acc[mi][ni] = zero;

  stage(0, 0);
#pragma unroll 2
  for (int cch = 0; cch < 72; ++cch) {
    __syncthreads();                 // drains this chunk's DMA; frees the other buffer
    if (cch < 71) stage(cch + 1, (cch + 1) & 1);
    const int b = cch & 1;
    const char* Ab = (const char*)Alds + b*ABYTES;
    const char* Bb = (const char*)Blds + b*ABYTES;
#pragma unroll
    for (int kk = 0; kk < 2; ++kk) {
      bf16x8 af[4], bfr[4];
#pragma unroll
      for (int mi = 0; mi < 4; ++mi) {
        int r = wm*64 + mi*16 + (lane & 15);
        int gsg = kk*4 + quad;
        af[mi] = *(const bf16x8*)(Ab + r*128 + ((gsg ^ (r & 7))*16));
      }
#pragma unroll
      for (int ni = 0; ni < 4; ++ni) {
        int r = wn*64 + ni*16 + (lane & 15);
        int gsg = kk*4 + quad;
        bfr[ni] = *(const bf16x8*)(Bb + r*128 + ((gsg ^ (r & 7))*16));
      }
#pragma unroll
      for (int mi = 0; mi < 4; ++mi)
#pragma unroll
        for (int ni = 0; ni < 4; ++ni)
          acc[mi][ni] = __builtin_amdgcn_mfma_f32_16x16x32_bf16(af[mi], bfr[ni], acc[mi][ni], 0, 0, 0);
    }
  }

  // epilogue: D layout col(pixel)=lane&15, row(co)=(lane>>4)*4+reg
#pragma unroll
  for (int mi = 0; mi < 4; ++mi) {
#pragma unroll
    for (int reg = 0; reg < 4; ++reg) {
      int co = cob0 + wm*64 + mi*16 + quad*4 + reg;
      float bv = bias[co];
#pragma unroll
      for (int ni = 0; ni < 4; ++ni) {
        int gp  = pixb + wn*64 + ni*16 + (lane & 15);
        int n   = gp >> 10;
        int ohw = gp & 1023;
        float v = acc[mi][ni][reg] + bv;
        v = (v >= 0.f ? v : 0.2f*v) * 1.41421356f;
        out[(((size_t)n*C_OUT + co) << 10) + ohw] = v;
      }
    }
  }
}

extern "C" void kernel_launch(void* const* d_in, const int* in_sizes, int n_in,
                              void* d_out, int out_size, void* d_ws, size_t ws_size,
                              hipStream_t stream) {
  const float* x    = (const float*)d_in[0];
  const float* w    = (const float*)d_in[1];
  const float* bias = (const float*)d_in[2];
  // d_in[3] = fir; values fixed by module config ([1,3,3,1] outer /64), folded in.
  float* out = (float*)d_out;
  __hip_bfloat16* w2 = (__hip_bfloat16*)d_ws;
  __hip_bfloat16* yt = (__hip_bfloat16*)((char*)d_ws + W2_BYTES);

  prep_w_kernel<<<(W2_ELEMS + 255)/256, 256, 0, stream>>>(w, w2);
  blur_kernel<<<dim3(4, 16, 16), 256, 0, stream>>>(x, yt);
  conv_kernel<<<dim3(PIX/128, C_OUT/128), 256, 0, stream>>>(w2, yt, bias, out);
}

// Round 4
// 307.618 us; speedup vs baseline: 1.6254x; 1.0847x over previous
//
#include <hip/hip_runtime.h>
#include <hip/hip_bf16.h>
#include <stdint.h>

#define N_IMG 16
#define C_IN  512
#define C_OUT 512
#define H_IN  64
#define W_IN  64
#define OH    32
#define OW    32
#define PIX   (N_IMG*OH*OW)        // 16384

// padded blurred-activation layout: [n][h+1 (65)][par (2)][ow'+1 (33)][ci (512)] bf16
#define YPH 65
#define YPW 33

#define W2_ELEMS (9*C_OUT*C_IN)    // 2359296
#define W2_BYTES (W2_ELEMS*2)      // 4718592 (256B aligned)

typedef __attribute__((ext_vector_type(8))) __bf16 bf16x8;
typedef __attribute__((ext_vector_type(4))) float  f32x4;

__device__ inline void gload_lds16(const void* g, void* l) {
  __builtin_amdgcn_global_load_lds(
      (const __attribute__((address_space(1))) void*)g,
      (__attribute__((address_space(3))) void*)l, 16, 0, 0);
}

// ---------------- weight prep: w[co][ci][kh][kw]*f32 -> w2[t][co][ci] bf16 * (1/1536)
// thread per (co,ci): 9 contiguous float reads/lane, per-tap contiguous wave writes
__global__ __launch_bounds__(256) void prep_w_kernel(const float* __restrict__ w,
                                                     __hip_bfloat16* __restrict__ w2) {
  int id = blockIdx.x * 256 + threadIdx.x;     // (co*512+ci), 262144 total
  const float* p = w + (size_t)id * 9;
  float v[9];
#pragma unroll
  for (int t = 0; t < 9; ++t) v[t] = p[t] * (1.0f/1536.0f);
#pragma unroll
  for (int t = 0; t < 9; ++t)
    w2[(size_t)t*(C_OUT*C_IN) + id] = __float2bfloat16(v[t]);
}

// ---------------- FIR blur, separable, register-streaming + LDS transpose
// grid: (row-tile 0..7, cib 0..15, n 0..15), block 256. Also zeroes yt halo.
// thread: c = tid>>3 (ci in chunk), octet p8 = tid&7 (w = p8*8 .. +7)
__global__ __launch_bounds__(256) void blur_kernel(const float* __restrict__ x,
                                                   __hip_bfloat16* __restrict__ yt) {
  __shared__ float obuf[2][32][65];   // stride 65 -> 2-way bank aliasing (free)
  const int tid = threadIdx.x;
  const int c   = tid >> 3;
  const int p8  = tid & 7;
  const int w8  = p8 * 8;
  const int r0  = blockIdx.x * 8;
  const int cib = blockIdx.y;
  const int n   = blockIdx.z;
  const float* xc = x + ((size_t)(n*C_IN + cib*32 + c) * H_IN) * W_IN + w8;

  // ---- halo zeroing (merged zero_pad) ----
  {
    const uint4 z4 = {0u, 0u, 0u, 0u};
    if (tid < 16) {                       // col-halo cidx=0 for this block's 8 rows
      int hh  = r0 + (tid >> 1);
      int par = tid & 1;
      size_t slot = (((size_t)n*YPH + hh + 1)*2 + par)*YPW;
      uint4* p = (uint4*)(yt + slot*C_IN + cib*32);
      p[0]=z4; p[1]=z4; p[2]=z4; p[3]=z4; // 32 ci bf16 = 64 B
    }
    if (blockIdx.x == 0 && tid < 66) {    // row-halo ridx=0, all (par, c)
      int par = tid / 33;
      int cc  = tid - par*33;
      size_t slot = ((size_t)n*YPH*2 + par)*YPW + cc;
      uint4* p = (uint4*)(yt + slot*C_IN + cib*32);
      p[0]=z4; p[1]=z4; p[2]=z4; p[3]=z4;
    }
  }

  // repack mapping: 4 consecutive lanes cover one pixel's 64B (32 ci) write
  const int rp_oc  = tid & 3;
  const int rp_p   = tid >> 2;       // full-res col 0..63
  const int rp_par = rp_p & 1;
  const int rp_ch  = rp_p >> 1;

  float cur[8], nxt[8];
  float h1[8], h2[8], h3[8];         // horizontal-blurred rows r-1, r-2, r-3
#pragma unroll
  for (int j = 0; j < 8; ++j) { h1[j] = 0.f; h2[j] = 0.f; h3[j] = 0.f; }

  auto load_row = [&](int r, float* dst) {
    if (r >= 0 && r < H_IN) {
      const float4 a = *(const float4*)(xc + (size_t)r * W_IN);
      const float4 b = *(const float4*)(xc + (size_t)r * W_IN + 4);
      dst[0]=a.x; dst[1]=a.y; dst[2]=a.z; dst[3]=a.w;
      dst[4]=b.x; dst[5]=b.y; dst[6]=b.z; dst[7]=b.w;
    } else {
#pragma unroll
      for (int j = 0; j < 8; ++j) dst[j] = 0.f;
    }
  };

  load_row(r0 - 2, cur);
  for (int ri = 0; ri < 11; ++ri) {
    const int r = r0 - 2 + ri;
    if (ri < 10) load_row(r + 1, nxt);   // prefetch next row

    // horizontal 4-tap [1,3,3,1] via shuffles (neighbors within the 8-lane row group)
    float l2 = __shfl_up(cur[6], 1);
    float l1 = __shfl_up(cur[7], 1);
    float rr = __shfl_down(cur[0], 1);
    if (p8 == 0) { l2 = 0.f; l1 = 0.f; }
    if (p8 == 7) { rr = 0.f; }
    float hc[8];
    hc[0] = l2 + 3.f*(l1 + cur[0]) + cur[1];
    hc[1] = l1 + 3.f*(cur[0] + cur[1]) + cur[2];
#pragma unroll
    for (int j = 2; j < 7; ++j) hc[j] = cur[j-2] + 3.f*(cur[j-1] + cur[j]) + cur[j+1];
    hc[7] = cur[5] + 3.f*(cur[6] + cur[7]) + rr;

    if (ri >= 3) {
      const int h = r - 1;             // output row
      const int b = ri & 1;
#pragma unroll
      for (int j = 0; j < 8; ++j)
        obuf[b][c][w8 + j] = (h3[j] + 3.f*(h2[j] + h1[j]) + hc[j]) * (1.0f/64.0f);
      __syncthreads();
      alignas(16) __hip_bfloat16 t16[8];
#pragma unroll
      for (int j = 0; j < 8; ++j)
        t16[j] = __float2bfloat16(obuf[b][rp_oc*8 + j][rp_p]);
      size_t slot = ((size_t)(n*YPH + h + 1)*2 + rp_par)*YPW + rp_ch + 1;
      *(uint4*)(yt + slot*C_IN + cib*32 + rp_oc*8) = *(uint4*)t16;
      // no second barrier: double buffer + next iteration's barrier protects reuse
    }

    // rotate vertical window, advance prefetch
#pragma unroll
    for (int j = 0; j < 8; ++j) {
      h3[j] = h2[j]; h2[j] = h1[j]; h1[j] = hc[j]; cur[j] = nxt[j];
    }
  }
}

// ---------------- implicit-GEMM conv, single-barrier double-buffered K-loop
// out[co][pix] = sum_t sum_ci w2[t][co][ci]*y[pix(t)][ci]
#define ABYTES (128*64*2)   // 16384 B per buffer
__global__ __launch_bounds__(256, 2) void conv_kernel(const __hip_bfloat16* __restrict__ w2,
                            const __hip_bfloat16* __restrict__ yt,
                            const float* __restrict__ bias,
                            float* __restrict__ out) {
  __shared__ __hip_bfloat16 Alds[2][128*64];   // 2 x 16 KB, XOR seg swizzle
  __shared__ __hip_bfloat16 Blds[2][128*64];   // 2 x 16 KB
  const int tid  = threadIdx.x;
  const int lane = tid & 63;
  const int wv   = tid >> 6;     // 4 waves
  const int wm   = wv & 1;
  const int wn   = wv >> 1;
  const int cob0 = blockIdx.y * 128;
  const int pixb = blockIdx.x * 128;
  const int quad = lane >> 4;
  const int wvb  = tid & 192;    // wave*64

  // staging precompute: slot s = i*256+tid; row=s>>3, pos=s&7, loads gseg=pos^(row&7)
  size_t aoff[4];
  int    bseg8[4], bn65[4], boh2[4], bow_[4];
  int    ldsOff[4];
#pragma unroll
  for (int i = 0; i < 4; ++i) {
    int s = i*256 + tid;
    int r = s >> 3;
    int pp = s & 7;
    int gg = pp ^ (r & 7);
    aoff[i] = (size_t)(cob0 + r)*C_IN + gg*8;
    int gp = pixb + r;
    bn65[i] = (gp >> 10) * YPH;
    boh2[i] = ((gp >> 5) & 31) * 2;
    bow_[i] = gp & 31;
    bseg8[i] = gg*8;
    ldsOff[i] = (i*256 + wvb)*16;   // wave-uniform base; HW adds lane*16
  }

  // stage chunk c (c = t*8 + cib64) into buffer b
  auto stage = [&](int c, int b) {
    const int t   = c >> 3;
    const int cib = (c & 7) << 6;
    const int kh  = (t * 11) >> 5;          // t/3 for t in 0..8
    const int kw  = t - kh*3;
    const int par = (kw == 1) ? 0 : 1;
    const int d   = (kw == 0) ? 0 : 1;
    const __hip_bfloat16* wt = w2 + (size_t)t * (C_OUT*C_IN) + cib;
#pragma unroll
    for (int i = 0; i < 4; ++i)
      gload_lds16(wt + aoff[i], (char*)Alds + b*ABYTES + ldsOff[i]);
#pragma unroll
    for (int i = 0; i < 4; ++i) {
      size_t slot = ((size_t)(bn65[i] + boh2[i] + kh)*2 + par)*YPW + bow_[i] + d;
      gload_lds16(yt + slot*C_IN + bseg8[i] + cib, (char*)Blds + b*ABYTES + ldsOff[i]);
    }
  };

  f32x4 acc[4][4];
  const f32x4 zero = {0.f, 0.f, 0.f, 0.f};
#pragma unroll
  for (int mi = 0; mi < 4; ++mi)
#pragma unroll
    for (int ni = 0; ni < 4; ++ni) acc[mi][ni] = zero;

  stage(0, 0);
#pragma unroll 2
  for (int cch = 0; cch < 72; ++cch) {
    __syncthreads();                 // drains this chunk's DMA; frees the other buffer
    if (cch < 71) stage(cch + 1, (cch + 1) & 1);
    const int b = cch & 1;
    const char* Ab = (const char*)Alds + b*ABYTES;
    const char* Bb = (const char*)Blds + b*ABYTES;
#pragma unroll
    for (int kk = 0; kk < 2; ++kk) {
      bf16x8 af[4], bfr[4];
#pragma unroll
      for (int mi = 0; mi < 4; ++mi) {
        int r = wm*64 + mi*16 + (lane & 15);
        int gsg = kk*4 + quad;
        af[mi] = *(const bf16x8*)(Ab + r*128 + ((gsg ^ (r & 7))*16));
      }
#pragma unroll
      for (int ni = 0; ni < 4; ++ni) {
        int r = wn*64 + ni*16 + (lane & 15);
        int gsg = kk*4 + quad;
        bfr[ni] = *(const bf16x8*)(Bb + r*128 + ((gsg ^ (r & 7))*16));
      }
#pragma unroll
      for (int mi = 0; mi < 4; ++mi)
#pragma unroll
        for (int ni = 0; ni < 4; ++ni)
          acc[mi][ni] = __builtin_amdgcn_mfma_f32_16x16x32_bf16(af[mi], bfr[ni], acc[mi][ni], 0, 0, 0);
    }
  }

  // epilogue: D layout col(pixel)=lane&15, row(co)=(lane>>4)*4+reg
#pragma unroll
  for (int mi = 0; mi < 4; ++mi) {
#pragma unroll
    for (int reg = 0; reg < 4; ++reg) {
      int co = cob0 + wm*64 + mi*16 + quad*4 + reg;
      float bv = bias[co];
#pragma unroll
      for (int ni = 0; ni < 4; ++ni) {
        int gp  = pixb + wn*64 + ni*16 + (lane & 15);
        int n   = gp >> 10;
        int ohw = gp & 1023;
        float v = acc[mi][ni][reg] + bv;
        v = (v >= 0.f ? v : 0.2f*v) * 1.41421356f;
        out[(((size_t)n*C_OUT + co) << 10) + ohw] = v;
      }
    }
  }
}

extern "C" void kernel_launch(void* const* d_in, const int* in_sizes, int n_in,
                              void* d_out, int out_size, void* d_ws, size_t ws_size,
                              hipStream_t stream) {
  const float* x    = (const float*)d_in[0];
  const float* w    = (const float*)d_in[1];
  const float* bias = (const float*)d_in[2];
  // d_in[3] = fir; values fixed by module config ([1,3,3,1] outer /64), folded in.
  float* out = (float*)d_out;
  __hip_bfloat16* w2 = (__hip_bfloat16*)d_ws;
  __hip_bfloat16* yt = (__hip_bfloat16*)((char*)d_ws + W2_BYTES);

  prep_w_kernel<<<(C_OUT*C_IN)/256, 256, 0, stream>>>(w, w2);
  blur_kernel<<<dim3(8, 16, 16), 256, 0, stream>>>(x, yt);
  conv_kernel<<<dim3(PIX/128, C_OUT/128), 256, 0, stream>>>(w2, yt, bias, out);
}